// Round 10
// baseline (285.516 us; speedup 1.0000x reference)
//
#include <hip/hip_runtime.h>

// out[b,c,l,m] = sum_{s,t} xp[b,c,l+s] * F[c,s,t] * xp[b,c,m+t]
// x: [8,2,2048] f32, filt: [1,2,17,17] f32, out: [8,2,2048,2048] f32 (268 MB)
// HBM-write-bound: floor ~ 268MB / ~6.3 TB/s ~ 43 us of store time.
//
// v4 (6th submit; prior five runs hit broker timeouts): SINGLE fused kernel, no workspace.
//     - tile = 4 l-rows x full 2048 m per block (contiguous 32 KB write region)
//     - per block: threads 0..67 compute f[t][i] = sum_s xp[l0+i+s-8]*F[s][t]
//       (68 length-17 dots) into LDS sf[17][4] (272 B), one barrier.
//       Main loop reads sf[t] as same-address-broadcast ds_read_b128 (conflict-free).
//     - w-windows issued BEFORE the f-compute/barrier (latency hidden under it)
//     - plain f32x4 stores (v3 used nontemporal; fill proves plain stores
//       sustain 6.3 TB/s through L2/L3 write-back)
//     - each thread: 2 m-groups of 4 (m=4*tid, 4*tid+1024), 4 l-rows
//       -> every store instruction = 64 lanes x 16 B @ 16 B stride = 1 KB contiguous
//     Accumulation order (s ascending, then t ascending) identical to v3 -> bit-identical.

#define LN   2048
#define S    17
#define PADW 8
#define NBC  16

typedef float f32x4 __attribute__((ext_vector_type(4)));

__global__ __launch_bounds__(256) void filter_fused_kernel(
    const float* __restrict__ x,
    const float* __restrict__ filt,
    float* __restrict__ out)
{
    const int bc = blockIdx.z;
    const int c  = bc & 1;
    const int l0 = blockIdx.y * 4;
    const int tid = threadIdx.x;

    const float* __restrict__ xrow = x + (size_t)bc * LN;

    // ---- issue w-window loads first (independent of f-compute; hides latency) ----
    // two m-groups per thread: m1 = 4*tid, m2 = 4*tid + 1024
    const int m1 = 4 * tid;
    const int m2 = m1 + 1024;

    // w[i] = xp[m + i - 8], i = 0..19 (5 aligned 4-dword chunks each).
    // Chunk dword offset o = m - 8 + 4k is a multiple of 4; the valid region
    // [0, 2048) has multiple-of-4 boundaries -> chunks are never partial.
    float w1[20], w2[20];
#pragma unroll
    for (int k = 0; k < 5; k++) {
        const int o1 = m1 - PADW + 4 * k;
        const int o2 = m2 - PADW + 4 * k;
        f32x4 v1, v2;
        if (o1 >= 0 && o1 < LN) v1 = *reinterpret_cast<const f32x4*>(xrow + o1);
        else                    v1 = f32x4{0.0f, 0.0f, 0.0f, 0.0f};
        if (o2 >= 0 && o2 < LN) v2 = *reinterpret_cast<const f32x4*>(xrow + o2);
        else                    v2 = f32x4{0.0f, 0.0f, 0.0f, 0.0f};
        *reinterpret_cast<f32x4*>(&w1[4 * k]) = v1;
        *reinterpret_cast<f32x4*>(&w2[4 * k]) = v2;
    }

    // ---- cooperative f-compute: sf[t][i] = sum_s xp[l0+i+s-8] * F[c][s][t] ----
    __shared__ __align__(16) float sf[S][4];   // 272 B
    if (tid < S * 4) {
        const int t = tid >> 2;       // 0..16
        const int i = tid & 3;        // 0..3
        const float* __restrict__ Fc = filt + c * S * S;
        float a = 0.0f;
#pragma unroll
        for (int s = 0; s < S; s++) {
            const int j = l0 + i + s - PADW;
            const float xv = (j >= 0 && j < LN) ? xrow[j] : 0.0f;
            a += xv * Fc[s * S + t];   // s ascending: same order as v3's xf_kernel
        }
        sf[t][i] = a;
    }
    __syncthreads();

    // ---- main loop: 17 broadcast LDS reads, 544 FMAs ----
    float acc1[4][4] = {};
    float acc2[4][4] = {};
#pragma unroll
    for (int t = 0; t < S; t++) {
        // same address across ALL lanes -> LDS broadcast, conflict-free
        const f32x4 f = *reinterpret_cast<const f32x4*>(&sf[t][0]);
#pragma unroll
        for (int j = 0; j < 4; j++) {
            const float b1 = w1[t + j];
            const float b2 = w2[t + j];
#pragma unroll
            for (int i = 0; i < 4; i++) {
                acc1[i][j] += f[i] * b1;
                acc2[i][j] += f[i] * b2;
            }
        }
    }

    // ---- stores: per instruction 64 lanes x 16 B @ 16 B stride = 1 KB contiguous;
    //      whole block covers one contiguous 32 KB region. Plain stores (not nt).
    const size_t base = ((size_t)bc * LN + (size_t)l0) * LN;
#pragma unroll
    for (int li = 0; li < 4; li++) {
        f32x4 u1 = { acc1[li][0], acc1[li][1], acc1[li][2], acc1[li][3] };
        f32x4 u2 = { acc2[li][0], acc2[li][1], acc2[li][2], acc2[li][3] };
        float* p = out + base + (size_t)li * LN;
        *reinterpret_cast<f32x4*>(p + m1) = u1;
        *reinterpret_cast<f32x4*>(p + m2) = u2;
    }
}

extern "C" void kernel_launch(void* const* d_in, const int* in_sizes, int n_in,
                              void* d_out, int out_size, void* d_ws, size_t ws_size,
                              hipStream_t stream) {
    const float* x    = (const float*)d_in[0];   // [8,2,2048]
    const float* filt = (const float*)d_in[1];   // [1,2,17,17]
    float* out = (float*)d_out;                  // [8,2,2048,2048]
    (void)d_ws; (void)ws_size;

    filter_fused_kernel<<<dim3(1, LN / 4, NBC), 256, 0, stream>>>(x, filt, out);
}

// Round 13
// 273.750 us; speedup vs baseline: 1.0430x; 1.0430x over previous
//
#include <hip/hip_runtime.h>

// out[b,c,l,m] = sum_{s,t} xp[b,c,l+s] * F[c,s,t] * xp[b,c,m+t]
// x: [8,2,2048] f32, filt: [1,2,17,17] f32, out: [8,2,2048,2048] f32 (268 MB)
// HBM-write-bound: floor ~ 268MB / ~6.5 TB/s ~ 42 us of store time.
//
// v5 (3rd submit; prior runs hit broker timeouts): single-variable A/B vs v4 —
//     fused structure UNCHANGED, stores back to NONTEMPORAL (v3's mode).
//     v4 (fused+plain, our-portion ~122us) regressed vs v3 (two-kernel+nt,
//     ~104us); the confound was {fusion, store-mode}. This isolates store-mode.
//     Theory: out (268MB) ~ L3 (256MB) -> plain stores write-allocate near
//     capacity and thrash; nt streams past L3.
//     - tile = 4 l-rows x full 2048 m per block (contiguous 32 KB write region)
//     - threads 0..67 compute f[t][i] = sum_s xp[l0+i+s-8]*F[s][t] into LDS
//       sf[17][4] (272 B), one barrier; main loop reads sf[t] as
//       same-address-broadcast ds_read_b128 (conflict-free)
//     - w-windows issued BEFORE the f-compute/barrier (latency hidden under it)
//     - each thread: 2 m-groups of 4 (m=4*tid, 4*tid+1024), 4 l-rows
//       -> every store instruction = 64 lanes x 16 B @ 16 B stride = 1 KB contiguous
//     Accumulation order (s ascending, then t ascending) identical -> bit-identical.

#define LN   2048
#define S    17
#define PADW 8
#define NBC  16

typedef float f32x4 __attribute__((ext_vector_type(4)));

__global__ __launch_bounds__(256) void filter_fused_kernel(
    const float* __restrict__ x,
    const float* __restrict__ filt,
    float* __restrict__ out)
{
    const int bc = blockIdx.z;
    const int c  = bc & 1;
    const int l0 = blockIdx.y * 4;
    const int tid = threadIdx.x;

    const float* __restrict__ xrow = x + (size_t)bc * LN;

    // ---- issue w-window loads first (independent of f-compute; hides latency) ----
    // two m-groups per thread: m1 = 4*tid, m2 = 4*tid + 1024
    const int m1 = 4 * tid;
    const int m2 = m1 + 1024;

    // w[i] = xp[m + i - 8], i = 0..19 (5 aligned 4-dword chunks each).
    // Chunk dword offset o = m - 8 + 4k is a multiple of 4; the valid region
    // [0, 2048) has multiple-of-4 boundaries -> chunks are never partial.
    float w1[20], w2[20];
#pragma unroll
    for (int k = 0; k < 5; k++) {
        const int o1 = m1 - PADW + 4 * k;
        const int o2 = m2 - PADW + 4 * k;
        f32x4 v1, v2;
        if (o1 >= 0 && o1 < LN) v1 = *reinterpret_cast<const f32x4*>(xrow + o1);
        else                    v1 = f32x4{0.0f, 0.0f, 0.0f, 0.0f};
        if (o2 >= 0 && o2 < LN) v2 = *reinterpret_cast<const f32x4*>(xrow + o2);
        else                    v2 = f32x4{0.0f, 0.0f, 0.0f, 0.0f};
        *reinterpret_cast<f32x4*>(&w1[4 * k]) = v1;
        *reinterpret_cast<f32x4*>(&w2[4 * k]) = v2;
    }

    // ---- cooperative f-compute: sf[t][i] = sum_s xp[l0+i+s-8] * F[c][s][t] ----
    __shared__ __align__(16) float sf[S][4];   // 272 B
    if (tid < S * 4) {
        const int t = tid >> 2;       // 0..16
        const int i = tid & 3;        // 0..3
        const float* __restrict__ Fc = filt + c * S * S;
        float a = 0.0f;
#pragma unroll
        for (int s = 0; s < S; s++) {
            const int j = l0 + i + s - PADW;
            const float xv = (j >= 0 && j < LN) ? xrow[j] : 0.0f;
            a += xv * Fc[s * S + t];   // s ascending: same order as before
        }
        sf[t][i] = a;
    }
    __syncthreads();

    // ---- main loop: 17 broadcast LDS reads, 544 FMAs ----
    float acc1[4][4] = {};
    float acc2[4][4] = {};
#pragma unroll
    for (int t = 0; t < S; t++) {
        // same address across ALL lanes -> LDS broadcast, conflict-free
        const f32x4 f = *reinterpret_cast<const f32x4*>(&sf[t][0]);
#pragma unroll
        for (int j = 0; j < 4; j++) {
            const float b1 = w1[t + j];
            const float b2 = w2[t + j];
#pragma unroll
            for (int i = 0; i < 4; i++) {
                acc1[i][j] += f[i] * b1;
                acc2[i][j] += f[i] * b2;
            }
        }
    }

    // ---- stores: per instruction 64 lanes x 16 B @ 16 B stride = 1 KB contiguous;
    //      whole block covers one contiguous 32 KB region. NONTEMPORAL (v3 mode).
    const size_t base = ((size_t)bc * LN + (size_t)l0) * LN;
#pragma unroll
    for (int li = 0; li < 4; li++) {
        f32x4 u1 = { acc1[li][0], acc1[li][1], acc1[li][2], acc1[li][3] };
        f32x4 u2 = { acc2[li][0], acc2[li][1], acc2[li][2], acc2[li][3] };
        float* p = out + base + (size_t)li * LN;
        __builtin_nontemporal_store(u1, reinterpret_cast<f32x4*>(p + m1));
        __builtin_nontemporal_store(u2, reinterpret_cast<f32x4*>(p + m2));
    }
}

extern "C" void kernel_launch(void* const* d_in, const int* in_sizes, int n_in,
                              void* d_out, int out_size, void* d_ws, size_t ws_size,
                              hipStream_t stream) {
    const float* x    = (const float*)d_in[0];   // [8,2,2048]
    const float* filt = (const float*)d_in[1];   // [1,2,17,17]
    float* out = (float*)d_out;                  // [8,2,2048,2048]
    (void)d_ws; (void)ws_size;

    filter_fused_kernel<<<dim3(1, LN / 4, NBC), 256, 0, stream>>>(x, filt, out);
}